// Round 1
// baseline (420.041 us; speedup 1.0000x reference)
//
#include <hip/hip_runtime.h>

// SparseMinCostFlow on MI355X.
// N=8192 nodes, E=262144 edges, 10 flow iterations, dense NxN fp32 output.
//
// Structure:
//   zero_f4        : zero the 256 MB output (memory-bound floor ~40us)
//   zero_f4 (ws)   : zero 10 inflow buffers (10 * 8192 floats) in d_ws
//   flow_iter x9   : gather inflow_{i-1}[rows[e]] -> relu(.-d)*values[e]
//                    -> atomicAdd into inflow_i[cols[e]]
//   flow_final     : same gather, scatter-add into dense out[r*N + c]
//
// inflow_0 stays all-zero (represents flow0 == zeros), so iteration 1 needs
// no special-casing.

#define NN 8192
#define EE 262144

__global__ void zero_f4(float4* __restrict__ p, long n4) {
    long i = (long)blockIdx.x * blockDim.x + threadIdx.x;
    long stride = (long)gridDim.x * blockDim.x;
    float4 z = make_float4(0.f, 0.f, 0.f, 0.f);
    for (; i < n4; i += stride) p[i] = z;
}

__global__ void flow_iter(const float* __restrict__ values,
                          const float* __restrict__ d,
                          const int* __restrict__ rows,
                          const int* __restrict__ cols,
                          const float* __restrict__ inflow_prev,
                          float* __restrict__ inflow_next) {
    int e = blockIdx.x * blockDim.x + threadIdx.x;
    if (e >= EE) return;
    int r = rows[e];
    float adj = fmaxf(inflow_prev[r] - d[r], 0.f);
    float f = values[e] * adj;
    atomicAdd(&inflow_next[cols[e]], f);
}

__global__ void flow_final(const float* __restrict__ values,
                           const float* __restrict__ d,
                           const int* __restrict__ rows,
                           const int* __restrict__ cols,
                           const float* __restrict__ inflow_prev,
                           float* __restrict__ out) {
    int e = blockIdx.x * blockDim.x + threadIdx.x;
    if (e >= EE) return;
    int r = rows[e];
    float adj = fmaxf(inflow_prev[r] - d[r], 0.f);
    float f = values[e] * adj;
    atomicAdd(&out[(long)r * NN + cols[e]], f);
}

extern "C" void kernel_launch(void* const* d_in, const int* in_sizes, int n_in,
                              void* d_out, int out_size, void* d_ws, size_t ws_size,
                              hipStream_t stream) {
    const float* values = (const float*)d_in[0];
    const float* d      = (const float*)d_in[1];   // demands, N floats
    const int*   rows   = (const int*)d_in[2];
    const int*   cols   = (const int*)d_in[3];
    float* out = (float*)d_out;

    // Workspace layout: 10 inflow buffers of N floats each.
    // inflow_0 stays zero; iter i (1..9) writes inflow_i; final reads inflow_9.
    float* inflow = (float*)d_ws;                  // 10 * 8192 * 4 = 320 KiB

    // 1) Zero the dense output (64M floats = 16M float4).
    long out_n4 = (long)NN * NN / 4;
    zero_f4<<<4096, 256, 0, stream>>>((float4*)out, out_n4);

    // 2) Zero the inflow buffers (81920 floats = 20480 float4).
    long ws_n4 = (long)10 * NN / 4;
    zero_f4<<<80, 256, 0, stream>>>((float4*)inflow, ws_n4);

    // 3) Flow iterations 1..9: gather from inflow_{i-1}, scatter into inflow_i.
    const int blocks = EE / 256;
    for (int i = 1; i <= 9; ++i) {
        flow_iter<<<blocks, 256, 0, stream>>>(values, d, rows, cols,
                                              inflow + (long)(i - 1) * NN,
                                              inflow + (long)i * NN);
    }

    // 4) Iteration 10: scatter final flow into the dense output.
    flow_final<<<blocks, 256, 0, stream>>>(values, d, rows, cols,
                                           inflow + 9L * NN, out);
}